// Round 1
// baseline (1692.825 us; speedup 1.0000x reference)
//
#include <hip/hip_runtime.h>
#include <hip/hip_bf16.h>
#include <math.h>

// Problem constants (reference: B=4, D=1024, N=2048, K=1024, fp32)
#define BB 4
#define DD 1024
#define NN 2048
#define KK 1024

// ---------------------------------------------------------------------------
// Generic 64x64 tiled fp32 GEMM, 256 threads, 4x4 micro-tile, BK=16.
// MODE 0: C[m,n] = sum_k A[k*lda+m] * B[k*ldb+n]        (A^T B)
// MODE 1: C[m,n] = sum_k A[m*lda+k] * B[k*ldb+n]        (A  B)
// MODE 2: C[m,n] = sum_k A[m*lda+k] * B[n*ldb+k]        (A  B^T)
// EPI  0: none; 1: causal mask (n>m -> -inf); 2: residual add R
// gridDim.z = batch; batchX = per-batch element stride.
// All dims assumed divisible by 64 (M,N) and 16 (Kd) -- true for this problem.
// ---------------------------------------------------------------------------
template <int MODE, int EPI>
__global__ __launch_bounds__(256) void gemm64(
    const float* __restrict__ Ag, const float* __restrict__ Bg,
    const float* __restrict__ Rg, float* __restrict__ Cg,
    int M, int N, int Kd, int lda, int ldb, int ldc,
    long batchA, long batchB, long batchC, long batchR) {
  const int b = blockIdx.z;
  const float* A = Ag + (long)b * batchA;
  const float* Bp = Bg + (long)b * batchB;
  float* C = Cg + (long)b * batchC;
  const float* R = (EPI == 2) ? (Rg + (long)b * batchR) : nullptr;

  const int m0 = blockIdx.y * 64;
  const int n0 = blockIdx.x * 64;
  const int tid = threadIdx.x;
  const int tx = tid & 15;
  const int ty = tid >> 4;

  __shared__ float As[16][64];
  __shared__ float Bs[16][64];

  float acc[4][4] = {};

  for (int k0 = 0; k0 < Kd; k0 += 16) {
    // ---- load A tile into As[k][m] ----
    if (MODE == 0) {
      const int r = tid >> 4;          // k within tile
      const int c = (tid & 15) * 4;    // m within tile
      const float4 v = *(const float4*)(A + (long)(k0 + r) * lda + (m0 + c));
      As[r][c] = v.x; As[r][c + 1] = v.y; As[r][c + 2] = v.z; As[r][c + 3] = v.w;
    } else {
      const int r = tid >> 2;          // m within tile
      const int c = (tid & 3) * 4;     // k within tile
      const float4 v = *(const float4*)(A + (long)(m0 + r) * lda + (k0 + c));
      As[c][r] = v.x; As[c + 1][r] = v.y; As[c + 2][r] = v.z; As[c + 3][r] = v.w;
    }
    // ---- load B tile into Bs[k][n] ----
    if (MODE == 2) {
      const int r = tid >> 2;          // n within tile
      const int c = (tid & 3) * 4;     // k within tile
      const float4 v = *(const float4*)(Bp + (long)(n0 + r) * ldb + (k0 + c));
      Bs[c][r] = v.x; Bs[c + 1][r] = v.y; Bs[c + 2][r] = v.z; Bs[c + 3][r] = v.w;
    } else {
      const int r = tid >> 4;          // k within tile
      const int c = (tid & 15) * 4;    // n within tile
      const float4 v = *(const float4*)(Bp + (long)(k0 + r) * ldb + (n0 + c));
      Bs[r][c] = v.x; Bs[r][c + 1] = v.y; Bs[r][c + 2] = v.z; Bs[r][c + 3] = v.w;
    }
    __syncthreads();

#pragma unroll
    for (int kk = 0; kk < 16; ++kk) {
      float a[4], bv[4];
#pragma unroll
      for (int i = 0; i < 4; ++i) a[i] = As[kk][ty * 4 + i];
#pragma unroll
      for (int j = 0; j < 4; ++j) bv[j] = Bs[kk][tx * 4 + j];
#pragma unroll
      for (int i = 0; i < 4; ++i)
#pragma unroll
        for (int j = 0; j < 4; ++j) acc[i][j] += a[i] * bv[j];
    }
    __syncthreads();
  }

#pragma unroll
  for (int i = 0; i < 4; ++i) {
    const int m = m0 + ty * 4 + i;
#pragma unroll
    for (int j = 0; j < 4; ++j) {
      const int n = n0 + tx * 4 + j;
      float v = acc[i][j];
      if (EPI == 1) {
        if (n > m) v = -INFINITY;
      }
      if (EPI == 2) {
        v += R[(long)m * ldc + n];
      }
      C[(long)m * ldc + n] = v;
    }
  }
}

// ---------------------------------------------------------------------------
// In-place causal row softmax. One 256-thread block per row (b*N + i).
// Masked entries already hold -inf, so a full-row softmax is correct
// (exp(-inf - max) == 0; diagonal always valid so max is finite).
// ---------------------------------------------------------------------------
__global__ __launch_bounds__(256) void softmax_rows(float* __restrict__ L, int n) {
  const long row = blockIdx.x;
  float* p = L + row * (long)n;
  const int tid = threadIdx.x;
  __shared__ float red[256];

  float m = -INFINITY;
  for (int j = tid; j < n; j += 256) m = fmaxf(m, p[j]);
  red[tid] = m;
  __syncthreads();
  for (int s = 128; s > 0; s >>= 1) {
    if (tid < s) red[tid] = fmaxf(red[tid], red[tid + s]);
    __syncthreads();
  }
  m = red[0];
  __syncthreads();

  float sum = 0.0f;
  for (int j = tid; j < n; j += 256) {
    const float e = __expf(p[j] - m);
    p[j] = e;
    sum += e;
  }
  red[tid] = sum;
  __syncthreads();
  for (int s = 128; s > 0; s >>= 1) {
    if (tid < s) red[tid] += red[tid + s];
    __syncthreads();
  }
  const float inv = 1.0f / red[0];
  for (int j = tid; j < n; j += 256) p[j] *= inv;
}

// ---------------------------------------------------------------------------
// Pipeline:
//  1. M_QK = W_Q^T W_K  (D x D),  M_OV = W_O^T W_V  (D x D)
//  2. t      = M_QK * x           (B, D, N)
//  3. logits = x^T t  + causal    (B, N, N)
//  4. A      = softmax(logits)    in place
//  5. ctx    = x * A^T            (B, D, N)
//  6. out    = x + M_OV * ctx     (B, D, N)
// Workspace: 2*D*D + 2*B*D*N + B*N*N floats = ~136 MB.
// ---------------------------------------------------------------------------
extern "C" void kernel_launch(void* const* d_in, const int* in_sizes, int n_in,
                              void* d_out, int out_size, void* d_ws, size_t ws_size,
                              hipStream_t stream) {
  const float* x = (const float*)d_in[0];
  const float* WQ = (const float*)d_in[1];
  const float* WK = (const float*)d_in[2];
  const float* WV = (const float*)d_in[3];
  const float* WO = (const float*)d_in[4];
  float* out = (float*)d_out;

  float* ws = (float*)d_ws;
  float* Mqk = ws;                           // D*D
  float* Mov = Mqk + (long)DD * DD;          // D*D
  float* t = Mov + (long)DD * DD;            // B*D*N
  float* Lg = t + (long)BB * DD * NN;        // B*N*N
  float* ctx = Lg + (long)BB * NN * NN;      // B*D*N

  const long xBatch = (long)DD * NN;
  const long lBatch = (long)NN * NN;
  const dim3 blk(256);

  // 1. fused weight products (K-contraction over KK)
  gemm64<0, 0><<<dim3(DD / 64, DD / 64, 1), blk, 0, stream>>>(
      WQ, WK, nullptr, Mqk, DD, DD, KK, DD, DD, DD, 0, 0, 0, 0);
  gemm64<0, 0><<<dim3(DD / 64, DD / 64, 1), blk, 0, stream>>>(
      WO, WV, nullptr, Mov, DD, DD, KK, DD, DD, DD, 0, 0, 0, 0);

  // 2. t = M_QK * x   (per batch)
  gemm64<1, 0><<<dim3(NN / 64, DD / 64, BB), blk, 0, stream>>>(
      Mqk, x, nullptr, t, DD, NN, DD, DD, NN, NN, 0, xBatch, xBatch, 0);

  // 3. logits = x^T t with causal mask
  gemm64<0, 1><<<dim3(NN / 64, NN / 64, BB), blk, 0, stream>>>(
      x, t, nullptr, Lg, NN, NN, DD, NN, NN, NN, xBatch, xBatch, lBatch, 0);

  // 4. softmax rows
  softmax_rows<<<dim3(BB * NN), blk, 0, stream>>>(Lg, NN);

  // 5. ctx = x * A^T
  gemm64<2, 0><<<dim3(NN / 64, DD / 64, BB), blk, 0, stream>>>(
      x, Lg, nullptr, ctx, DD, NN, NN, NN, NN, NN, xBatch, lBatch, xBatch, 0);

  // 6. out = x + M_OV * ctx
  gemm64<1, 2><<<dim3(NN / 64, DD / 64, BB), blk, 0, stream>>>(
      Mov, ctx, x, out, DD, NN, DD, DD, NN, NN, 0, xBatch, xBatch, xBatch);
}

// Round 2
// 508.344 us; speedup vs baseline: 3.3301x; 3.3301x over previous
//
#include <hip/hip_runtime.h>
#include <hip/hip_bf16.h>
#include <math.h>

// Problem constants: B=4, D=1024, N=2048, K=1024, fp32 in/out.
#define BB 4
#define DD 1024
#define NN 2048
#define KK 1024
#define NT128 16            // NN/128
#define NTRI 136            // 16*17/2 lower-triangular 128x128 tiles
#define TRI_ELEMS 16384     // 128*128

typedef __attribute__((ext_vector_type(4))) float f32x4;
typedef __attribute__((ext_vector_type(8))) short bfrag;

__device__ __forceinline__ ushort f2b(float f) {  // fp32 -> bf16 RNE
  union { float f; unsigned u; } c; c.f = f;
  unsigned u = c.u + 0x7fffu + ((c.u >> 16) & 1u);
  return (ushort)(u >> 16);
}
__device__ __forceinline__ float b2f(ushort h) {
  union { unsigned u; float f; } c; c.u = ((unsigned)h) << 16;
  return c.f;
}

// ---------------------------------------------------------------------------
// x [b][d][n] fp32 -> x_hi (bf16, same layout), xT_hi/xT_lo (bf16, [b][n][d])
// ---------------------------------------------------------------------------
__global__ __launch_bounds__(256) void transpose_split(
    const float* __restrict__ x, ushort* __restrict__ xhi,
    ushort* __restrict__ xTh, ushort* __restrict__ xTl) {
  const int b = blockIdx.z;
  const int n0 = blockIdx.x * 32, d0 = blockIdx.y * 32;
  const int tx = threadIdx.x, ty = threadIdx.y;
  __shared__ float tile[32][33];
  const float* xb = x + (long)b * DD * NN;
  ushort* xhb = xhi + (long)b * DD * NN;
#pragma unroll
  for (int r = 0; r < 4; ++r) {
    const int dl = ty + r * 8;
    const float v = xb[(long)(d0 + dl) * NN + n0 + tx];
    tile[dl][tx] = v;
    xhb[(long)(d0 + dl) * NN + n0 + tx] = f2b(v);
  }
  __syncthreads();
#pragma unroll
  for (int r = 0; r < 4; ++r) {
    const int nl = ty + r * 8;
    const float v = tile[tx][nl];
    const ushort h = f2b(v);
    const long o = (long)b * NN * DD + (long)(n0 + nl) * DD + d0 + tx;
    xTh[o] = h;
    xTl[o] = f2b(v - b2f(h));
  }
}

// ---------------------------------------------------------------------------
// Weight products (fp32 VALU, small): C[m,n] = sum_k A[k][m]*B[k][n], DxD, K=KK
// EPI 0: split bf16 store (hi/lo). EPI 1: bf16 store (hi only).
// ---------------------------------------------------------------------------
template <int EPI>
__global__ __launch_bounds__(256) void gemm64w(
    const float* __restrict__ A, const float* __restrict__ Bp,
    ushort* __restrict__ Ch, ushort* __restrict__ Cl) {
  const int m0 = blockIdx.y * 64, n0 = blockIdx.x * 64;
  const int tid = threadIdx.x, tx = tid & 15, ty = tid >> 4;
  __shared__ float As[16][64], Bs[16][64];
  float acc[4][4] = {};
  for (int k0 = 0; k0 < KK; k0 += 16) {
    const int r = tid >> 4, c = (tid & 15) * 4;
    const float4 va = *(const float4*)(A + (long)(k0 + r) * DD + m0 + c);
    As[r][c] = va.x; As[r][c + 1] = va.y; As[r][c + 2] = va.z; As[r][c + 3] = va.w;
    const float4 vb = *(const float4*)(Bp + (long)(k0 + r) * DD + n0 + c);
    Bs[r][c] = vb.x; Bs[r][c + 1] = vb.y; Bs[r][c + 2] = vb.z; Bs[r][c + 3] = vb.w;
    __syncthreads();
#pragma unroll
    for (int kk = 0; kk < 16; ++kk) {
      float a[4], bv[4];
#pragma unroll
      for (int i = 0; i < 4; ++i) a[i] = As[kk][ty * 4 + i];
#pragma unroll
      for (int j = 0; j < 4; ++j) bv[j] = Bs[kk][tx * 4 + j];
#pragma unroll
      for (int i = 0; i < 4; ++i)
#pragma unroll
        for (int j = 0; j < 4; ++j) acc[i][j] += a[i] * bv[j];
    }
    __syncthreads();
  }
#pragma unroll
  for (int i = 0; i < 4; ++i) {
    const int m = m0 + ty * 4 + i;
#pragma unroll
    for (int j = 0; j < 4; ++j) {
      const int n = n0 + tx * 4 + j;
      const float v = acc[i][j];
      const ushort h = f2b(v);
      Ch[(long)m * DD + n] = h;
      if (EPI == 0) Cl[(long)m * DD + n] = f2b(v - b2f(h));
    }
  }
}

// ---------------------------------------------------------------------------
// bf16 MFMA GEMM, 128x128 block tile, 4 waves (2x2) of 64x64, BK=32,
// 16x16x32 MFMA. All operands k-contiguous: lane frag = 8 consecutive k.
// Fragment layouts (HW-verified, learn_hip m89):
//   A[m=lane&15][k=quad*8+j], B[n=lane&15][k=quad*8+j],
//   C/D: col=lane&15, row=quad*4+reg.
// SPLIT=1: operands have hi+lo bf16 arrays; 3 MFMAs (hh, hl, lh) ~= fp32.
// EPI 0: split bf16 store (C0=hi, C1=lo), row-major ld=ldc
// EPI 1: triangular-tile fp32 store (1D grid over B*NTRI lower tiles)
// EPI 2: bf16 store; A staged from triangular tile layout; K limited to m0+128
// EPI 3: fp32 store with residual add from Res
// ---------------------------------------------------------------------------
template <int SPLIT, int EPI>
__global__ __launch_bounds__(256) void gemm_mfma(
    const ushort* __restrict__ Ah, const ushort* __restrict__ Al,
    const ushort* __restrict__ Bh, const ushort* __restrict__ Bl,
    void* __restrict__ C0, void* __restrict__ C1, const float* __restrict__ Res,
    int M, int N, int K, int lda, int ldb, int ldc,
    long bA, long bB, long bC, long bR) {
  extern __shared__ ushort smem[];
  ushort* sAh = smem;                                   // 128 rows x stride 40
  ushort* sBh = smem + (SPLIT ? 10240 : 5120);
  ushort* sAl = SPLIT ? smem + 5120 : nullptr;
  ushort* sBl = SPLIT ? smem + 15360 : nullptr;

  int b, m0, n0, tiC = 0;
  if (EPI == 1) {
    int t = blockIdx.x;
    b = t / NTRI; t -= b * NTRI;
    int ti = 0;
    while ((ti + 1) * (ti + 2) / 2 <= t) ++ti;
    const int tj = t - ti * (ti + 1) / 2;
    m0 = ti * 128; n0 = tj * 128; tiC = t;
  } else {
    b = blockIdx.z; m0 = blockIdx.y * 128; n0 = blockIdx.x * 128;
  }
  const int kmax = (EPI == 2) ? (m0 + 128) : K;
  int triA0 = 0;
  if (EPI == 2) { const int ti = m0 >> 7; triA0 = ti * (ti + 1) / 2; }

  const ushort* A_h = Ah + (long)b * bA;
  const ushort* B_h = Bh + (long)b * bB;
  const ushort* A_l = SPLIT ? Al + (long)b * bA : nullptr;
  const ushort* B_l = SPLIT ? Bl + (long)b * bB : nullptr;

  const int tid = threadIdx.x;
  const int lane = tid & 63, wave = tid >> 6;
  const int wm = (wave & 1) * 64, wn = (wave >> 1) * 64;
  const int r16 = lane & 15, quad = lane >> 4;

  f32x4 acc[4][4];
#pragma unroll
  for (int i = 0; i < 4; ++i)
#pragma unroll
    for (int j = 0; j < 4; ++j) acc[i][j] = (f32x4){0.f, 0.f, 0.f, 0.f};

  for (int k0 = 0; k0 < kmax; k0 += 32) {
    __syncthreads();
#pragma unroll
    for (int it = 0; it < 2; ++it) {
      const int chunk = tid + it * 256;           // 512 chunks of 8 bf16
      const int rr = chunk >> 2, c8 = (chunk & 3) * 8;
      long aoff;
      if (EPI == 2)
        aoff = (long)(triA0 + (k0 >> 7)) * TRI_ELEMS + (long)rr * 128 + (k0 & 127) + c8;
      else
        aoff = (long)(m0 + rr) * lda + k0 + c8;
      const long boff = (long)(n0 + rr) * ldb + k0 + c8;
      *(int4*)&sAh[rr * 40 + c8] = *(const int4*)&A_h[aoff];
      *(int4*)&sBh[rr * 40 + c8] = *(const int4*)&B_h[boff];
      if (SPLIT) {
        *(int4*)&sAl[rr * 40 + c8] = *(const int4*)&A_l[aoff];
        *(int4*)&sBl[rr * 40 + c8] = *(const int4*)&B_l[boff];
      }
    }
    __syncthreads();

    bfrag ah[4], bh[4], al[4], bl[4];
#pragma unroll
    for (int t4 = 0; t4 < 4; ++t4) {
      ah[t4] = *(const bfrag*)&sAh[(wm + t4 * 16 + r16) * 40 + quad * 8];
      bh[t4] = *(const bfrag*)&sBh[(wn + t4 * 16 + r16) * 40 + quad * 8];
      if (SPLIT) {
        al[t4] = *(const bfrag*)&sAl[(wm + t4 * 16 + r16) * 40 + quad * 8];
        bl[t4] = *(const bfrag*)&sBl[(wn + t4 * 16 + r16) * 40 + quad * 8];
      }
    }
#pragma unroll
    for (int mt = 0; mt < 4; ++mt)
#pragma unroll
      for (int nt = 0; nt < 4; ++nt) {
        acc[mt][nt] = __builtin_amdgcn_mfma_f32_16x16x32_bf16(ah[mt], bh[nt], acc[mt][nt], 0, 0, 0);
        if (SPLIT) {
          acc[mt][nt] = __builtin_amdgcn_mfma_f32_16x16x32_bf16(ah[mt], bl[nt], acc[mt][nt], 0, 0, 0);
          acc[mt][nt] = __builtin_amdgcn_mfma_f32_16x16x32_bf16(al[mt], bh[nt], acc[mt][nt], 0, 0, 0);
        }
      }
  }

  // epilogue
#pragma unroll
  for (int mt = 0; mt < 4; ++mt)
#pragma unroll
    for (int nt = 0; nt < 4; ++nt)
#pragma unroll
      for (int reg = 0; reg < 4; ++reg) {
        const int ml = wm + mt * 16 + quad * 4 + reg;
        const int nl = wn + nt * 16 + r16;
        const float v = acc[mt][nt][reg];
        if (EPI == 0) {
          ushort* Ch = (ushort*)C0 + (long)b * bC;
          ushort* Cl = (ushort*)C1 + (long)b * bC;
          const long o = (long)(m0 + ml) * ldc + n0 + nl;
          const ushort h = f2b(v);
          Ch[o] = h;
          Cl[o] = f2b(v - b2f(h));
        } else if (EPI == 1) {
          float* C = (float*)C0 + (long)b * bC + (long)tiC * TRI_ELEMS;
          C[ml * 128 + nl] = v;
        } else if (EPI == 2) {
          ushort* C = (ushort*)C0 + (long)b * bC;
          C[(long)(m0 + ml) * ldc + n0 + nl] = f2b(v);
        } else {
          float* C = (float*)C0 + (long)b * bC;
          const float* R = Res + (long)b * bR;
          const long o = (long)(m0 + ml) * ldc + n0 + nl;
          C[o] = R[o] + v;
        }
      }
}

// ---------------------------------------------------------------------------
// Causal softmax over triangular-tiled logits. One block per row (b, i).
// Row i: valid cols j <= i (tiles tj=0..ti). Writes bf16 A in same tri layout,
// zero-filling diagonal-tile cols (i, (ti+1)*128) so the ctx GEMM can read
// whole 128-wide k-tiles.
// ---------------------------------------------------------------------------
__global__ __launch_bounds__(256) void softmax_tri(
    const float* __restrict__ L, ushort* __restrict__ Aout) {
  const int row = blockIdx.x;
  const int b = row >> 11, i = row & (NN - 1);
  const int ti = i >> 7, ml = i & 127;
  const long base = (long)b * ((long)NTRI * TRI_ELEMS);
  const int trib = ti * (ti + 1) / 2;
  const int len = i + 1;
  const int tot = (ti + 1) * 128;
  const int tid = threadIdx.x;
  __shared__ float red[256];
  float vv[8];
  float m = -INFINITY;
#pragma unroll
  for (int u = 0; u < 8; ++u) {
    const int j = tid + u * 256;
    if (j < len) {
      const float v = L[base + (long)(trib + (j >> 7)) * TRI_ELEMS + ml * 128 + (j & 127)];
      vv[u] = v;
      m = fmaxf(m, v);
    }
  }
  red[tid] = m; __syncthreads();
  for (int s = 128; s; s >>= 1) { if (tid < s) red[tid] = fmaxf(red[tid], red[tid + s]); __syncthreads(); }
  m = red[0]; __syncthreads();
  float sum = 0.f;
#pragma unroll
  for (int u = 0; u < 8; ++u) {
    const int j = tid + u * 256;
    if (j < len) { const float e = __expf(vv[u] - m); vv[u] = e; sum += e; }
  }
  red[tid] = sum; __syncthreads();
  for (int s = 128; s; s >>= 1) { if (tid < s) red[tid] += red[tid + s]; __syncthreads(); }
  const float inv = 1.f / red[0];
#pragma unroll
  for (int u = 0; u < 8; ++u) {
    const int j = tid + u * 256;
    if (j < tot) {
      const ushort o = (j < len) ? f2b(vv[u] * inv) : (ushort)0;
      Aout[base + (long)(trib + (j >> 7)) * TRI_ELEMS + ml * 128 + (j & 127)] = o;
    }
  }
}

// ---------------------------------------------------------------------------
// Pipeline (all operands k-contiguous by construction):
//  0. x -> x_hi [b][d][n], xT_hi/lo [b][n][d]
//  1. Mqk = WQ^T WK (split bf16), Mov = WO^T WV (bf16)      [fp32 VALU, small]
//  2. tT[i,d] = sum_e xT[i,e] Mqk[d,e]          split MFMA, split-stored
//  3. logits[i,j] = sum_d xT[i,d] tT[j,d]       split MFMA, lower tri tiles
//  4. A = causal softmax (bf16, tri layout, zero-padded diag tiles)
//  5. ctxT[i,e] = sum_{t<=i} A[i,t] x[e,t]      bf16 MFMA, causal K-limit
//  6. out[d,i] = x[d,i] + sum_e Mov[d,e] ctxT[i,e]   bf16 MFMA + residual
// Workspace ~122 MB; tT region reused for A, logits region reused for ctxT.
// ---------------------------------------------------------------------------
extern "C" void kernel_launch(void* const* d_in, const int* in_sizes, int n_in,
                              void* d_out, int out_size, void* d_ws, size_t ws_size,
                              hipStream_t stream) {
  const float* x = (const float*)d_in[0];
  const float* WQ = (const float*)d_in[1];
  const float* WK = (const float*)d_in[2];
  const float* WV = (const float*)d_in[3];
  const float* WO = (const float*)d_in[4];
  float* out = (float*)d_out;

  const long XE = (long)BB * DD * NN;  // 8M elements
  ushort* x_hi = (ushort*)d_ws;
  ushort* xTh = x_hi + XE;
  ushort* xTl = xTh + XE;
  ushort* mqk_h = xTl + XE;
  ushort* mqk_l = mqk_h + (long)DD * DD;
  ushort* mov_h = mqk_l + (long)DD * DD;
  ushort* tTh = mov_h + (long)DD * DD;
  ushort* tTl = tTh + XE;
  float* logits = (float*)(tTl + XE);
  ushort* A_tri = tTh;            // overlays tT (dead after step 3)
  ushort* ctxT = (ushort*)logits; // overlays logits (dead after softmax)
  const long TRIB = (long)NTRI * TRI_ELEMS;

  transpose_split<<<dim3(NN / 32, DD / 32, BB), dim3(32, 8), 0, stream>>>(x, x_hi, xTh, xTl);
  gemm64w<0><<<dim3(16, 16), 256, 0, stream>>>(WQ, WK, mqk_h, mqk_l);
  gemm64w<1><<<dim3(16, 16), 256, 0, stream>>>(WO, WV, mov_h, nullptr);

  // tT = xT * Mqk^T (split)
  gemm_mfma<1, 0><<<dim3(DD / 128, NN / 128, BB), 256, 40960, stream>>>(
      xTh, xTl, mqk_h, mqk_l, tTh, tTl, nullptr,
      NN, DD, DD, DD, DD, DD, XE / BB, 0, XE / BB, 0);

  // logits (lower tri tiles)
  gemm_mfma<1, 1><<<dim3(BB * NTRI), 256, 40960, stream>>>(
      xTh, xTl, tTh, tTl, logits, nullptr, nullptr,
      NN, NN, DD, DD, DD, 0, XE / BB, XE / BB, TRIB, 0);

  softmax_tri<<<dim3(BB * NN), 256, 0, stream>>>(logits, A_tri);

  // ctxT = A * x^T (causal K-limit)
  gemm_mfma<0, 2><<<dim3(DD / 128, NN / 128, BB), 256, 20480, stream>>>(
      A_tri, nullptr, x_hi, nullptr, ctxT, nullptr, nullptr,
      NN, DD, NN, 0, NN, DD, TRIB, XE / BB, XE / BB, 0);

  // out = x + Mov * ctx
  gemm_mfma<0, 3><<<dim3(NN / 128, DD / 128, BB), 256, 20480, stream>>>(
      mov_h, nullptr, ctxT, nullptr, out, nullptr, x,
      DD, NN, DD, DD, DD, NN, 0, XE / BB, XE / BB, XE / BB);
}

// Round 3
// 449.196 us; speedup vs baseline: 3.7686x; 1.1317x over previous
//
#include <hip/hip_runtime.h>
#include <hip/hip_bf16.h>
#include <math.h>

// Problem constants: B=4, D=1024, N=2048, K=1024, fp32 in/out.
#define BB 4
#define DD 1024
#define NN 2048
#define KK 1024
#define NT128 16            // NN/128
#define NTRI 136            // 16*17/2 lower-triangular 128x128 tiles
#define TRI_ELEMS 16384     // 128*128

typedef __attribute__((ext_vector_type(4))) float f32x4;
typedef __attribute__((ext_vector_type(8))) short bfrag;

typedef __attribute__((address_space(1))) const unsigned int gu32;
typedef __attribute__((address_space(3))) unsigned int lu32;

// async global->LDS, 16B per lane; LDS dest = base + lane*16 (wave-uniform base)
__device__ __forceinline__ void async16(const void* g, void* l) {
  __builtin_amdgcn_global_load_lds((gu32*)g, (lu32*)l, 16, 0, 0);
}

__device__ __forceinline__ ushort f2b(float f) {  // fp32 -> bf16 RNE
  union { float f; unsigned u; } c; c.f = f;
  unsigned u = c.u + 0x7fffu + ((c.u >> 16) & 1u);
  return (ushort)(u >> 16);
}
__device__ __forceinline__ float b2f(ushort h) {
  union { unsigned u; float f; } c; c.u = ((unsigned)h) << 16;
  return c.f;
}

// ---------------------------------------------------------------------------
// x [b][d][n] fp32 -> x_hi (bf16, same layout), xT_hi/xT_lo (bf16, [b][n][d])
// ---------------------------------------------------------------------------
__global__ __launch_bounds__(256) void transpose_split(
    const float* __restrict__ x, ushort* __restrict__ xhi,
    ushort* __restrict__ xTh, ushort* __restrict__ xTl) {
  const int b = blockIdx.z;
  const int n0 = blockIdx.x * 32, d0 = blockIdx.y * 32;
  const int tx = threadIdx.x, ty = threadIdx.y;
  __shared__ float tile[32][33];
  const float* xb = x + (long)b * DD * NN;
  ushort* xhb = xhi + (long)b * DD * NN;
#pragma unroll
  for (int r = 0; r < 4; ++r) {
    const int dl = ty + r * 8;
    const float v = xb[(long)(d0 + dl) * NN + n0 + tx];
    tile[dl][tx] = v;
    xhb[(long)(d0 + dl) * NN + n0 + tx] = f2b(v);
  }
  __syncthreads();
#pragma unroll
  for (int r = 0; r < 4; ++r) {
    const int nl = ty + r * 8;
    const float v = tile[tx][nl];
    const ushort h = f2b(v);
    const long o = (long)b * NN * DD + (long)(n0 + nl) * DD + d0 + tx;
    xTh[o] = h;
    xTl[o] = f2b(v - b2f(h));
  }
}

// ---------------------------------------------------------------------------
// W (K x D fp32, row-major [k][d]) -> WT [d][k] bf16 hi (+lo if SPLIT)
// ---------------------------------------------------------------------------
template <int SPLIT>
__global__ __launch_bounds__(256) void wtrans(
    const float* __restrict__ W, ushort* __restrict__ Th, ushort* __restrict__ Tl) {
  const int k0 = blockIdx.x * 32, d0 = blockIdx.y * 32;
  const int tx = threadIdx.x, ty = threadIdx.y;
  __shared__ float tile[32][33];
#pragma unroll
  for (int r = 0; r < 4; ++r) {
    const int kl = ty + r * 8;
    tile[kl][tx] = W[(long)(k0 + kl) * DD + d0 + tx];
  }
  __syncthreads();
#pragma unroll
  for (int r = 0; r < 4; ++r) {
    const int dl = ty + r * 8;
    const float v = tile[tx][dl];                // = W[k0+tx][d0+dl]
    const ushort h = f2b(v);
    const long o = (long)(d0 + dl) * KK + k0 + tx;
    Th[o] = h;
    if (SPLIT) Tl[o] = f2b(v - b2f(h));
  }
}

// ---------------------------------------------------------------------------
// bf16 MFMA GEMM, 128x128 block tile, 4 waves (2x2) of 64x64, BK=32,
// 16x16x32 MFMA, global_load_lds(16B) staging into packed LDS [128][32].
// Fragment layouts (HW-verified, learn_hip m89):
//   A[m=lane&15][k=quad*8+j], B[n=lane&15][k=quad*8+j],
//   C/D: col=lane&15, row=quad*4+reg.
// SPLIT: hi+lo bf16 operands, 3 MFMAs (hh, hl, lh) ~= fp32 accuracy.
// TRIA : A staged from triangular tile layout; K limited to m0+128.
// STORE 0: split bf16 (C0=hi, C1=lo), row-major ldc
//       1: triangular-tile fp32 (1D grid over B*NTRI lower tiles)
//       2: bf16 row-major
//       3: fp32 row-major with residual add from Res
// ---------------------------------------------------------------------------
template <int SPLIT, int TRIA, int STORE>
__global__ __launch_bounds__(256) void gemm_mfma(
    const ushort* __restrict__ Ah, const ushort* __restrict__ Al,
    const ushort* __restrict__ Bh, const ushort* __restrict__ Bl,
    void* __restrict__ C0, void* __restrict__ C1, const float* __restrict__ Res,
    int K, int lda, int ldb, int ldc,
    long bA, long bB, long bC, long bR) {
  extern __shared__ ushort smem[];
  ushort* sAh = smem;                                    // [128][32] 8KB
  ushort* sBh = smem + (SPLIT ? 8192 : 4096);
  ushort* sAl = SPLIT ? smem + 4096 : nullptr;
  ushort* sBl = SPLIT ? smem + 12288 : nullptr;

  int b, m0, n0, tiC = 0;
  if (STORE == 1) {
    int t = blockIdx.x;
    b = t / NTRI; t -= b * NTRI;
    int ti = 0;
    while ((ti + 1) * (ti + 2) / 2 <= t) ++ti;
    const int tj = t - ti * (ti + 1) / 2;
    m0 = ti * 128; n0 = tj * 128; tiC = t;
  } else {
    b = blockIdx.z; m0 = blockIdx.y * 128; n0 = blockIdx.x * 128;
  }
  const int kmax = TRIA ? (m0 + 128) : K;
  int triA0 = 0;
  if (TRIA) { const int ti = m0 >> 7; triA0 = ti * (ti + 1) / 2; }

  const ushort* A_h = Ah + (long)b * bA;
  const ushort* B_h = Bh + (long)b * bB;
  const ushort* A_l = SPLIT ? Al + (long)b * bA : nullptr;
  const ushort* B_l = SPLIT ? Bl + (long)b * bB : nullptr;

  const int tid = threadIdx.x;
  const int lane = tid & 63, wave = tid >> 6;
  const int wm = (wave & 1) * 64, wn = (wave >> 1) * 64;
  const int r16 = lane & 15, quad = lane >> 4;

  f32x4 acc[4][4];
#pragma unroll
  for (int i = 0; i < 4; ++i)
#pragma unroll
    for (int j = 0; j < 4; ++j) acc[i][j] = (f32x4){0.f, 0.f, 0.f, 0.f};

  for (int k0 = 0; k0 < kmax; k0 += 32) {
    __syncthreads();
    {
      const int kc = (lane & 3) * 8;      // k-elems within 32 (16B chunk)
#pragma unroll
      for (int c = 0; c < 2; ++c) {
        const int seg = wave * 2 + c;     // 16-row group 0..7
        const int row = seg * 16 + (lane >> 2);
        long aoff;
        if (TRIA)
          aoff = (long)(triA0 + (k0 >> 7)) * TRI_ELEMS + (long)row * 128 + (k0 & 127) + kc;
        else
          aoff = (long)(m0 + row) * lda + k0 + kc;
        const long boff = (long)(n0 + row) * ldb + k0 + kc;
        async16(A_h + aoff, sAh + seg * 512);
        async16(B_h + boff, sBh + seg * 512);
        if (SPLIT) {
          async16(A_l + aoff, sAl + seg * 512);
          async16(B_l + boff, sBl + seg * 512);
        }
      }
    }
    __syncthreads();

    bfrag ah[4], bh[4], al[4], bl[4];
#pragma unroll
    for (int t4 = 0; t4 < 4; ++t4) {
      ah[t4] = *(const bfrag*)&sAh[(wm + t4 * 16 + r16) * 32 + quad * 8];
      bh[t4] = *(const bfrag*)&sBh[(wn + t4 * 16 + r16) * 32 + quad * 8];
      if (SPLIT) {
        al[t4] = *(const bfrag*)&sAl[(wm + t4 * 16 + r16) * 32 + quad * 8];
        bl[t4] = *(const bfrag*)&sBl[(wn + t4 * 16 + r16) * 32 + quad * 8];
      }
    }
#pragma unroll
    for (int mt = 0; mt < 4; ++mt)
#pragma unroll
      for (int nt = 0; nt < 4; ++nt) {
        acc[mt][nt] = __builtin_amdgcn_mfma_f32_16x16x32_bf16(ah[mt], bh[nt], acc[mt][nt], 0, 0, 0);
        if (SPLIT) {
          acc[mt][nt] = __builtin_amdgcn_mfma_f32_16x16x32_bf16(ah[mt], bl[nt], acc[mt][nt], 0, 0, 0);
          acc[mt][nt] = __builtin_amdgcn_mfma_f32_16x16x32_bf16(al[mt], bh[nt], acc[mt][nt], 0, 0, 0);
        }
      }
  }

  // epilogue
#pragma unroll
  for (int mt = 0; mt < 4; ++mt)
#pragma unroll
    for (int nt = 0; nt < 4; ++nt)
#pragma unroll
      for (int reg = 0; reg < 4; ++reg) {
        const int ml = wm + mt * 16 + quad * 4 + reg;
        const int nl = wn + nt * 16 + r16;
        const float v = acc[mt][nt][reg];
        if (STORE == 0) {
          ushort* Ch = (ushort*)C0 + (long)b * bC;
          ushort* Cl = (ushort*)C1 + (long)b * bC;
          const long o = (long)(m0 + ml) * ldc + n0 + nl;
          const ushort h = f2b(v);
          Ch[o] = h;
          Cl[o] = f2b(v - b2f(h));
        } else if (STORE == 1) {
          float* C = (float*)C0 + (long)b * bC + (long)tiC * TRI_ELEMS;
          C[ml * 128 + nl] = v;
        } else if (STORE == 2) {
          ushort* C = (ushort*)C0 + (long)b * bC;
          C[(long)(m0 + ml) * ldc + n0 + nl] = f2b(v);
        } else {
          float* C = (float*)C0 + (long)b * bC;
          const float* R = Res + (long)b * bR;
          const long o = (long)(m0 + ml) * ldc + n0 + nl;
          C[o] = R[o] + v;
        }
      }
}

// ---------------------------------------------------------------------------
// Causal softmax over triangular-tiled logits. One block per row (b, i).
// Writes bf16 A in tri layout, zero-filling diagonal-tile cols beyond i.
// ---------------------------------------------------------------------------
__global__ __launch_bounds__(256) void softmax_tri(
    const float* __restrict__ L, ushort* __restrict__ Aout) {
  const int row = blockIdx.x;
  const int b = row >> 11, i = row & (NN - 1);
  const int ti = i >> 7, ml = i & 127;
  const long base = (long)b * ((long)NTRI * TRI_ELEMS);
  const int trib = ti * (ti + 1) / 2;
  const int len = i + 1;
  const int tot = (ti + 1) * 128;
  const int tid = threadIdx.x;
  __shared__ float red[256];
  float vv[8];
  float m = -INFINITY;
#pragma unroll
  for (int u = 0; u < 8; ++u) {
    const int j = tid + u * 256;
    if (j < len) {
      const float v = L[base + (long)(trib + (j >> 7)) * TRI_ELEMS + ml * 128 + (j & 127)];
      vv[u] = v;
      m = fmaxf(m, v);
    }
  }
  red[tid] = m; __syncthreads();
  for (int s = 128; s; s >>= 1) { if (tid < s) red[tid] = fmaxf(red[tid], red[tid + s]); __syncthreads(); }
  m = red[0]; __syncthreads();
  float sum = 0.f;
#pragma unroll
  for (int u = 0; u < 8; ++u) {
    const int j = tid + u * 256;
    if (j < len) { const float e = __expf(vv[u] - m); vv[u] = e; sum += e; }
  }
  red[tid] = sum; __syncthreads();
  for (int s = 128; s; s >>= 1) { if (tid < s) red[tid] += red[tid + s]; __syncthreads(); }
  const float inv = 1.f / red[0];
#pragma unroll
  for (int u = 0; u < 8; ++u) {
    const int j = tid + u * 256;
    if (j < tot) {
      const ushort o = (j < len) ? f2b(vv[u] * inv) : (ushort)0;
      Aout[base + (long)(trib + (j >> 7)) * TRI_ELEMS + ml * 128 + (j & 127)] = o;
    }
  }
}

// ---------------------------------------------------------------------------
// Pipeline (all MFMA operands k-contiguous by construction):
//  0. x -> x_hi [b][d][n], xT hi/lo [b][n][d];  W_Q..W_O -> WT [d][k] bf16
//  1. Mqk = WQT x WKT^T (split MFMA, split store), Mov = WOT x WVT^T (bf16)
//  2. tT[i,d] = sum_e xT[i,e] Mqk[d,e]          split MFMA, split store
//  3. logits[i,j] = sum_d xT[i,d] tT[j,d]       split MFMA, lower tri tiles
//  4. A = causal softmax (bf16, tri layout, zero-padded diag tiles)
//  5. ctxT[i,e] = sum_{t<=i} A[i,t] x[e,t]      bf16 MFMA, causal K-limit
//  6. out[d,i] = x[d,i] + sum_e Mov[d,e] ctxT[i,e]   bf16 MFMA + residual
// ---------------------------------------------------------------------------
extern "C" void kernel_launch(void* const* d_in, const int* in_sizes, int n_in,
                              void* d_out, int out_size, void* d_ws, size_t ws_size,
                              hipStream_t stream) {
  const float* x = (const float*)d_in[0];
  const float* WQ = (const float*)d_in[1];
  const float* WK = (const float*)d_in[2];
  const float* WV = (const float*)d_in[3];
  const float* WO = (const float*)d_in[4];
  float* out = (float*)d_out;

  const long XE = (long)BB * DD * NN;    // 8M elements
  const long WE = (long)DD * KK;         // 1M elements
  ushort* x_hi = (ushort*)d_ws;
  ushort* xTh = x_hi + XE;
  ushort* xTl = xTh + XE;
  ushort* wqT_h = xTl + XE;
  ushort* wqT_l = wqT_h + WE;
  ushort* wkT_h = wqT_l + WE;
  ushort* wkT_l = wkT_h + WE;
  ushort* wvT_h = wkT_l + WE;
  ushort* woT_h = wvT_h + WE;
  ushort* mqk_h = woT_h + WE;
  ushort* mqk_l = mqk_h + WE;
  ushort* mov_h = mqk_l + WE;
  ushort* tTh = mov_h + WE;
  ushort* tTl = tTh + XE;
  float* logits = (float*)(tTl + XE);    // B*NTRI*TRI_ELEMS fp32 (~35.7MB)
  ushort* A_tri = tTh;                   // overlays tT hi+lo (dead after step 3)
  ushort* ctxT = (ushort*)logits;        // overlays logits (dead after softmax)
  const long TRIB = (long)NTRI * TRI_ELEMS;
  const long XB = XE / BB;

  transpose_split<<<dim3(NN / 32, DD / 32, BB), dim3(32, 8), 0, stream>>>(x, x_hi, xTh, xTl);
  wtrans<1><<<dim3(KK / 32, DD / 32), dim3(32, 8), 0, stream>>>(WQ, wqT_h, wqT_l);
  wtrans<1><<<dim3(KK / 32, DD / 32), dim3(32, 8), 0, stream>>>(WK, wkT_h, wkT_l);
  wtrans<0><<<dim3(KK / 32, DD / 32), dim3(32, 8), 0, stream>>>(WV, wvT_h, nullptr);
  wtrans<0><<<dim3(KK / 32, DD / 32), dim3(32, 8), 0, stream>>>(WO, woT_h, nullptr);

  // Mqk = WQT * WKT^T (split, split store)
  gemm_mfma<1, 0, 0><<<dim3(DD / 128, DD / 128, 1), 256, 32768, stream>>>(
      wqT_h, wqT_l, wkT_h, wkT_l, mqk_h, mqk_l, nullptr,
      KK, KK, KK, DD, 0, 0, 0, 0);
  // Mov = WOT * WVT^T (plain bf16)
  gemm_mfma<0, 0, 2><<<dim3(DD / 128, DD / 128, 1), 256, 16384, stream>>>(
      woT_h, nullptr, wvT_h, nullptr, mov_h, nullptr, nullptr,
      KK, KK, KK, DD, 0, 0, 0, 0);

  // tT = xT * Mqk^T (split)
  gemm_mfma<1, 0, 0><<<dim3(DD / 128, NN / 128, BB), 256, 32768, stream>>>(
      xTh, xTl, mqk_h, mqk_l, tTh, tTl, nullptr,
      DD, DD, DD, DD, XB, 0, XB, 0);

  // logits (lower tri tiles)
  gemm_mfma<1, 0, 1><<<dim3(BB * NTRI), 256, 32768, stream>>>(
      xTh, xTl, tTh, tTl, logits, nullptr, nullptr,
      DD, DD, DD, 0, XB, XB, TRIB, 0);

  softmax_tri<<<dim3(BB * NN), 256, 0, stream>>>(logits, A_tri);

  // ctxT = A * x^T (tri A, causal K-limit)
  gemm_mfma<0, 1, 2><<<dim3(DD / 128, NN / 128, BB), 256, 16384, stream>>>(
      A_tri, nullptr, x_hi, nullptr, ctxT, nullptr, nullptr,
      NN, 0, NN, DD, TRIB, XB, XB, 0);

  // out = x + Mov * ctx
  gemm_mfma<0, 0, 3><<<dim3(NN / 128, DD / 128, BB), 256, 16384, stream>>>(
      mov_h, nullptr, ctxT, nullptr, out, nullptr, x,
      DD, DD, DD, NN, 0, XB, XB, XB);
}